// Round 1
// baseline (342.601 us; speedup 1.0000x reference)
//
#include <hip/hip_runtime.h>
#include <hip/hip_bf16.h>

#define T_SEQ 2048
#define NBATCH 8
#define EMB 1024
#define HD 128

typedef _Float16 f16_t;
typedef _Float16 f16x8 __attribute__((ext_vector_type(8)));
typedef float f32x4 __attribute__((ext_vector_type(4)));

#define NEG_INF (-__builtin_inff())

// ---------------------------------------------------------------------------
// Kernel 1: pack Wq*scale | Wk | Wv transposed into Wt[384][1024] fp16,
// and biases (bq*scale | bk | bv) into biasc[384] fp32.
// ---------------------------------------------------------------------------
__global__ __launch_bounds__(256) void prep_w(
    const float* __restrict__ Wk, const float* __restrict__ bk,
    const float* __restrict__ Wq, const float* __restrict__ bq,
    const float* __restrict__ Wv, const float* __restrict__ bv,
    f16_t* __restrict__ Wt, float* __restrict__ biasc) {
    int n = blockIdx.x;  // 0..383
    const float scale = 0.08838834764831845f;  // HEAD^-0.5
    const float* W; const float* bias; float sc; int col;
    if (n < 128)      { W = Wq; bias = bq; sc = scale; col = n; }
    else if (n < 256) { W = Wk; bias = bk; sc = 1.0f;  col = n - 128; }
    else              { W = Wv; bias = bv; sc = 1.0f;  col = n - 256; }
    for (int kk = threadIdx.x; kk < EMB; kk += 256)
        Wt[n * EMB + kk] = (f16_t)(W[kk * HD + col] * sc);
    if (threadIdx.x == 0) biasc[n] = bias[col] * sc;
}

// ---------------------------------------------------------------------------
// Kernel 2: QKV projection GEMM. C[16384,384] = X[16384,1024] @ W[1024,384].
// 128x128 tile per block (256 thr = 4 waves, each wave 64x64).
// X staged fp32->fp16 into LDS (stride 40 = 80B: 2-way-max bank aliasing).
// Epilogue: q,k row-major fp16; v stored transposed Vt[b][h][t].
// ---------------------------------------------------------------------------
__global__ __launch_bounds__(256) void qkv_gemm(
    const float* __restrict__ X, const f16_t* __restrict__ Wt,
    const float* __restrict__ biasc,
    f16_t* __restrict__ q, f16_t* __restrict__ k, f16_t* __restrict__ vt) {
    __shared__ f16_t Xs[128 * 40];

    int bid = blockIdx.x;
    int nt = bid / 128, mt = bid % 128;
    int m0 = mt * 128, n0 = nt * 128;
    int tid = threadIdx.x;
    int lane = tid & 63, w = tid >> 6;
    int quad = lane >> 4, l15 = lane & 15;
    int msub = (w & 1) * 64, nsub = (w >> 1) * 64;

    int r0 = tid >> 2;            // staging row (0..63), +64 for second group
    int c0 = (tid & 3) * 8;       // staging col chunk

    f32x4 acc[4][4] = {};

    for (int kc = 0; kc < EMB; kc += 32) {
        __syncthreads();
        #pragma unroll
        for (int gg = 0; gg < 2; ++gg) {
            int row = r0 + gg * 64;
            const float* src = X + (size_t)(m0 + row) * EMB + kc + c0;
            float4 f0 = *(const float4*)src;
            float4 f1 = *(const float4*)(src + 4);
            union { f16_t h[8]; uint4 u; } pk;
            pk.h[0] = (f16_t)f0.x; pk.h[1] = (f16_t)f0.y;
            pk.h[2] = (f16_t)f0.z; pk.h[3] = (f16_t)f0.w;
            pk.h[4] = (f16_t)f1.x; pk.h[5] = (f16_t)f1.y;
            pk.h[6] = (f16_t)f1.z; pk.h[7] = (f16_t)f1.w;
            *(uint4*)&Xs[row * 40 + c0] = pk.u;
        }
        __syncthreads();

        f16x8 afr[4];
        #pragma unroll
        for (int mf = 0; mf < 4; ++mf)
            afr[mf] = *(const f16x8*)&Xs[(msub + mf * 16 + l15) * 40 + quad * 8];
        #pragma unroll
        for (int nf = 0; nf < 4; ++nf) {
            f16x8 bfr = *(const f16x8*)(Wt + (size_t)(n0 + nsub + nf * 16 + l15) * EMB + kc + quad * 8);
            #pragma unroll
            for (int mf = 0; mf < 4; ++mf)
                acc[mf][nf] = __builtin_amdgcn_mfma_f32_16x16x32_f16(afr[mf], bfr, acc[mf][nf], 0, 0, 0);
        }
    }

    // epilogue
    #pragma unroll
    for (int nf = 0; nf < 4; ++nf) {
        int ng = n0 + nsub + nf * 16 + l15;   // 0..383
        float bval = biasc[ng];
        #pragma unroll
        for (int mf = 0; mf < 4; ++mf) {
            int rowg = m0 + msub + mf * 16 + quad * 4;
            f32x4 a = acc[mf][nf];
            #pragma unroll
            for (int r = 0; r < 4; ++r) {
                int row = rowg + r;           // flat (b*T + t)
                float val = a[r] + bval;
                if (ng < 128) {
                    q[(size_t)row * HD + ng] = (f16_t)val;
                } else if (ng < 256) {
                    k[(size_t)row * HD + (ng - 128)] = (f16_t)val;
                } else {
                    int b = row >> 11, tt = row & 2047;
                    vt[(size_t)b * HD * T_SEQ + (size_t)(ng - 256) * T_SEQ + tt] = (f16_t)val;
                }
            }
        }
    }
}

// ---------------------------------------------------------------------------
// Kernel 3: column softmax stats. For each column s: m_s = max_{t>=s} S[t,s],
// l_s = sum exp(S-m). Block = 16 columns; 4 waves split the t-tile range,
// online (m,l) per wave, combined in LDS. Stores (m_s, 1/l_s).
// ---------------------------------------------------------------------------
__global__ __launch_bounds__(256) void col_stats(
    const f16_t* __restrict__ q, const f16_t* __restrict__ k,
    float2* __restrict__ stats) {
    __shared__ float pm[4][16], pl[4][16];
    int bid = blockIdx.x;
    int b = bid >> 7;                 // 128 blocks per batch
    int sb = (bid & 127) << 4;        // column base (batch-local)
    int tid = threadIdx.x, lane = tid & 63, w = tid >> 6;
    int quad = lane >> 4, l15 = lane & 15;
    size_t base = (size_t)b * T_SEQ;

    // B fragments: k rows sb..sb+15, resident across the whole t loop
    f16x8 bfr[4];
    const f16_t* krow = k + (base + sb + l15) * HD;
    #pragma unroll
    for (int c = 0; c < 4; ++c) bfr[c] = *(const f16x8*)(krow + c * 32 + quad * 8);

    float m = NEG_INF, l = 0.f;
    int ntiles = (T_SEQ - sb) >> 4;
    for (int it = w; it < ntiles; it += 4) {
        int t0 = sb + (it << 4);
        const f16_t* qrow = q + (base + t0 + l15) * HD;
        f32x4 s = {};
        #pragma unroll
        for (int c = 0; c < 4; ++c) {
            f16x8 afr = *(const f16x8*)(qrow + c * 32 + quad * 8);
            s = __builtin_amdgcn_mfma_f32_16x16x32_f16(afr, bfr[c], s, 0, 0, 0);
        }
        int scol = sb + l15;
        float sv[4]; float tm = NEG_INF;
        #pragma unroll
        for (int r = 0; r < 4; ++r) {
            int t = t0 + quad * 4 + r;
            float v = (t < scol) ? NEG_INF : s[r];   // mask only bites on diag tile
            sv[r] = v;
            tm = fmaxf(tm, v);
        }
        tm = fmaxf(tm, __shfl_xor(tm, 16, 64));
        tm = fmaxf(tm, __shfl_xor(tm, 32, 64));
        float mn = fmaxf(m, tm);
        float ssum = 0.f;
        #pragma unroll
        for (int r = 0; r < 4; ++r)
            ssum += (sv[r] == NEG_INF) ? 0.f : __expf(sv[r] - mn);
        ssum += __shfl_xor(ssum, 16, 64);
        ssum += __shfl_xor(ssum, 32, 64);
        l = l * __expf(m - mn) + ssum;
        m = mn;
    }
    if (quad == 0) { pm[w][l15] = m; pl[w][l15] = l; }
    __syncthreads();
    if (tid < 16) {
        float M = pm[0][tid];
        #pragma unroll
        for (int ww = 1; ww < 4; ++ww) M = fmaxf(M, pm[ww][tid]);
        float L = 0.f;
        #pragma unroll
        for (int ww = 0; ww < 4; ++ww)
            L += (pl[ww][tid] == 0.f) ? 0.f : pl[ww][tid] * __expf(pm[ww][tid] - M);
        stats[base + sb + tid] = make_float2(M, 1.0f / L);
    }
}

// ---------------------------------------------------------------------------
// Kernel 4: output pass. O[t,:] = sum_{s<=t} exp(S[t,s]-m_s)*invl_s * V[s,:].
// Block = 64 q-rows (wave = 16 rows), loop s-tiles of 32.
// P goes C-layout -> LDS (stride 40) -> A-layout for the PV MFMA.
// ---------------------------------------------------------------------------
__global__ __launch_bounds__(256) void attn_out(
    const f16_t* __restrict__ q, const f16_t* __restrict__ k,
    const f16_t* __restrict__ vt, const float2* __restrict__ stats,
    float* __restrict__ out) {
    __shared__ f16_t Pl[4][16 * 40];
    int bid = blockIdx.x;
    int b = bid >> 5, qt = bid & 31;   // 32 q-tile blocks per batch
    int tid = threadIdx.x, lane = tid & 63, w = tid >> 6;
    int quad = lane >> 4, l15 = lane & 15;
    size_t base = (size_t)b * T_SEQ;
    int trow = qt * 64 + w * 16;       // batch-local first q row of this wave

    // A fragments of q (16 rows x 128 k), resident
    f16x8 afr[4];
    const f16_t* qrow = q + (base + trow + l15) * HD;
    #pragma unroll
    for (int c = 0; c < 4; ++c) afr[c] = *(const f16x8*)(qrow + c * 32 + quad * 8);

    f32x4 o[8] = {};
    f16_t* myP = Pl[w];
    const f16_t* vbat = vt + (size_t)b * HD * T_SEQ;

    int niters = (trow + 47) >> 5;
    for (int it = 0; it < niters; ++it) {
        int sb = it << 5;
        #pragma unroll
        for (int sub = 0; sub < 2; ++sub) {
            f32x4 s = {};
            const f16_t* krow = k + (base + sb + sub * 16 + l15) * HD;
            #pragma unroll
            for (int c = 0; c < 4; ++c) {
                f16x8 bfr = *(const f16x8*)(krow + c * 32 + quad * 8);
                s = __builtin_amdgcn_mfma_f32_16x16x32_f16(afr[c], bfr, s, 0, 0, 0);
            }
            int scol = sb + sub * 16 + l15;
            float2 st = stats[base + scol];
            #pragma unroll
            for (int r = 0; r < 4; ++r) {
                int t = trow + quad * 4 + r;
                float p = __expf(s[r] - st.x) * st.y;
                if (scol > t) p = 0.f;   // causal mask
                myP[(quad * 4 + r) * 40 + sub * 16 + l15] = (f16_t)p;
            }
        }
        // P: C-layout in LDS -> A-layout fragment
        f16x8 pa = *(const f16x8*)&myP[l15 * 40 + quad * 8];
        const f16_t* vb = vbat + sb + quad * 8;
        #pragma unroll
        for (int nf = 0; nf < 8; ++nf) {
            f16x8 bfr = *(const f16x8*)(vb + (size_t)(nf * 16 + l15) * T_SEQ);
            o[nf] = __builtin_amdgcn_mfma_f32_16x16x32_f16(pa, bfr, o[nf], 0, 0, 0);
        }
    }

    #pragma unroll
    for (int nf = 0; nf < 8; ++nf) {
        #pragma unroll
        for (int r = 0; r < 4; ++r) {
            int row = trow + quad * 4 + r;
            out[(base + row) * HD + nf * 16 + l15] = o[nf][r];
        }
    }
}

// ---------------------------------------------------------------------------
extern "C" void kernel_launch(void* const* d_in, const int* in_sizes, int n_in,
                              void* d_out, int out_size, void* d_ws, size_t ws_size,
                              hipStream_t stream) {
    const float* X  = (const float*)d_in[0];
    const float* Wk = (const float*)d_in[1];
    const float* bk = (const float*)d_in[2];
    const float* Wq = (const float*)d_in[3];
    const float* bq = (const float*)d_in[4];
    const float* Wv = (const float*)d_in[5];
    const float* bv = (const float*)d_in[6];
    float* out = (float*)d_out;

    char* ws = (char*)d_ws;
    const size_t WT_B    = 384 * 1024 * 2;            // 786432
    const size_t BIAS_B  = 2048;                      // 384*4 padded
    const size_t QKV_B   = (size_t)NBATCH * T_SEQ * HD * 2;  // 4 MiB each
    f16_t* Wt    = (f16_t*)ws;
    float* biasc = (float*)(ws + WT_B);
    f16_t* qb    = (f16_t*)(ws + WT_B + BIAS_B);
    f16_t* kb    = (f16_t*)(ws + WT_B + BIAS_B + QKV_B);
    f16_t* vtb   = (f16_t*)(ws + WT_B + BIAS_B + 2 * QKV_B);
    float2* stats = (float2*)(ws + WT_B + BIAS_B + 3 * QKV_B);

    prep_w<<<dim3(384), dim3(256), 0, stream>>>(Wk, bk, Wq, bq, Wv, bv, Wt, biasc);
    qkv_gemm<<<dim3(384), dim3(256), 0, stream>>>(X, Wt, biasc, qb, kb, vtb);
    col_stats<<<dim3(NBATCH * T_SEQ / 16), dim3(256), 0, stream>>>(qb, kb, stats);
    attn_out<<<dim3(NBATCH * T_SEQ / 64), dim3(256), 0, stream>>>(qb, kb, vtb, stats, out);
}

// Round 2
// 323.226 us; speedup vs baseline: 1.0599x; 1.0599x over previous
//
#include <hip/hip_runtime.h>
#include <hip/hip_bf16.h>

#define T_SEQ 2048
#define NBATCH 8
#define EMB 1024
#define HD 128

typedef _Float16 f16_t;
typedef _Float16 f16x8 __attribute__((ext_vector_type(8)));
typedef float f32x4 __attribute__((ext_vector_type(4)));

#define NEG_INF (-__builtin_inff())

// ---------------------------------------------------------------------------
// Kernel 1: pack Wq*scale | Wk | Wv transposed into Wt[384][1024] fp16,
// and biases (bq*scale | bk | bv) into biasc[384] fp32.
// ---------------------------------------------------------------------------
__global__ __launch_bounds__(256) void prep_w(
    const float* __restrict__ Wk, const float* __restrict__ bk,
    const float* __restrict__ Wq, const float* __restrict__ bq,
    const float* __restrict__ Wv, const float* __restrict__ bv,
    f16_t* __restrict__ Wt, float* __restrict__ biasc) {
    int n = blockIdx.x;  // 0..383
    const float scale = 0.08838834764831845f;  // HEAD^-0.5
    const float* W; const float* bias; float sc; int col;
    if (n < 128)      { W = Wq; bias = bq; sc = scale; col = n; }
    else if (n < 256) { W = Wk; bias = bk; sc = 1.0f;  col = n - 128; }
    else              { W = Wv; bias = bv; sc = 1.0f;  col = n - 256; }
    for (int kk = threadIdx.x; kk < EMB; kk += 256)
        Wt[n * EMB + kk] = (f16_t)(W[kk * HD + col] * sc);
    if (threadIdx.x == 0) biasc[n] = bias[col] * sc;
}

// ---------------------------------------------------------------------------
// Kernel 2: QKV projection GEMM. C[16384,384] = X[16384,1024] @ W[1024,384].
// 128x128 tile per block (256 thr = 4 waves, each wave 64x64).
// ---------------------------------------------------------------------------
__global__ __launch_bounds__(256) void qkv_gemm(
    const float* __restrict__ X, const f16_t* __restrict__ Wt,
    const float* __restrict__ biasc,
    f16_t* __restrict__ q, f16_t* __restrict__ k, f16_t* __restrict__ vt) {
    __shared__ f16_t Xs[128 * 40];

    int bid = blockIdx.x;
    int nt = bid / 128, mt = bid % 128;
    int m0 = mt * 128, n0 = nt * 128;
    int tid = threadIdx.x;
    int lane = tid & 63, w = tid >> 6;
    int quad = lane >> 4, l15 = lane & 15;
    int msub = (w & 1) * 64, nsub = (w >> 1) * 64;

    int r0 = tid >> 2;            // staging row (0..63), +64 for second group
    int c0 = (tid & 3) * 8;       // staging col chunk

    f32x4 acc[4][4] = {};

    for (int kc = 0; kc < EMB; kc += 32) {
        __syncthreads();
        #pragma unroll
        for (int gg = 0; gg < 2; ++gg) {
            int row = r0 + gg * 64;
            const float* src = X + (size_t)(m0 + row) * EMB + kc + c0;
            float4 f0 = *(const float4*)src;
            float4 f1 = *(const float4*)(src + 4);
            union { f16_t h[8]; uint4 u; } pk;
            pk.h[0] = (f16_t)f0.x; pk.h[1] = (f16_t)f0.y;
            pk.h[2] = (f16_t)f0.z; pk.h[3] = (f16_t)f0.w;
            pk.h[4] = (f16_t)f1.x; pk.h[5] = (f16_t)f1.y;
            pk.h[6] = (f16_t)f1.z; pk.h[7] = (f16_t)f1.w;
            *(uint4*)&Xs[row * 40 + c0] = pk.u;
        }
        __syncthreads();

        f16x8 afr[4];
        #pragma unroll
        for (int mf = 0; mf < 4; ++mf)
            afr[mf] = *(const f16x8*)&Xs[(msub + mf * 16 + l15) * 40 + quad * 8];
        #pragma unroll
        for (int nf = 0; nf < 4; ++nf) {
            f16x8 bfr = *(const f16x8*)(Wt + (size_t)(n0 + nsub + nf * 16 + l15) * EMB + kc + quad * 8);
            #pragma unroll
            for (int mf = 0; mf < 4; ++mf)
                acc[mf][nf] = __builtin_amdgcn_mfma_f32_16x16x32_f16(afr[mf], bfr, acc[mf][nf], 0, 0, 0);
        }
    }

    // epilogue
    #pragma unroll
    for (int nf = 0; nf < 4; ++nf) {
        int ng = n0 + nsub + nf * 16 + l15;   // 0..383
        float bval = biasc[ng];
        #pragma unroll
        for (int mf = 0; mf < 4; ++mf) {
            int rowg = m0 + msub + mf * 16 + quad * 4;
            f32x4 a = acc[mf][nf];
            #pragma unroll
            for (int r = 0; r < 4; ++r) {
                int row = rowg + r;           // flat (b*T + t)
                float val = a[r] + bval;
                if (ng < 128) {
                    q[(size_t)row * HD + ng] = (f16_t)val;
                } else if (ng < 256) {
                    k[(size_t)row * HD + (ng - 128)] = (f16_t)val;
                } else {
                    int b = row >> 11, tt = row & 2047;
                    vt[(size_t)b * HD * T_SEQ + (size_t)(ng - 256) * T_SEQ + tt] = (f16_t)val;
                }
            }
        }
    }
}

// ---------------------------------------------------------------------------
// Kernel 3: column softmax stats, triangle-paired for load balance.
// Block = column-tiles {j, 127-j} (16 cols each); 4 waves split the combined
// 129 t-tiles round-robin, maintaining online (m,l) per tile; LDS combine.
// ---------------------------------------------------------------------------
__device__ __forceinline__ void cs_step(
    const f16_t* __restrict__ q, size_t base, int t0, int sbX,
    const f16x8 (&bfr)[4], float& m, float& l, int quad, int l15) {
    const f16_t* qrow = q + (base + t0 + l15) * HD;
    f32x4 s = {};
    #pragma unroll
    for (int c = 0; c < 4; ++c) {
        f16x8 afr = *(const f16x8*)(qrow + c * 32 + quad * 8);
        s = __builtin_amdgcn_mfma_f32_16x16x32_f16(afr, bfr[c], s, 0, 0, 0);
    }
    int scol = sbX + l15;
    float sv[4]; float tm = NEG_INF;
    #pragma unroll
    for (int r = 0; r < 4; ++r) {
        int t = t0 + quad * 4 + r;
        float v = (t < scol) ? NEG_INF : s[r];   // mask only bites on diag tile
        sv[r] = v;
        tm = fmaxf(tm, v);
    }
    tm = fmaxf(tm, __shfl_xor(tm, 16, 64));
    tm = fmaxf(tm, __shfl_xor(tm, 32, 64));
    float mn = fmaxf(m, tm);
    float ssum = 0.f;
    #pragma unroll
    for (int r = 0; r < 4; ++r)
        ssum += (sv[r] == NEG_INF) ? 0.f : __expf(sv[r] - mn);
    ssum += __shfl_xor(ssum, 16, 64);
    ssum += __shfl_xor(ssum, 32, 64);
    l = l * __expf(m - mn) + ssum;
    m = mn;
}

__global__ __launch_bounds__(256) void col_stats(
    const f16_t* __restrict__ q, const f16_t* __restrict__ k,
    float2* __restrict__ stats) {
    __shared__ float pm[2][4][16], pl[2][4][16];
    int bid = blockIdx.x;
    int b = bid >> 6, p = bid & 63;
    int j1 = p, j2 = 127 - p;
    int sb1 = j1 << 4, sb2 = j2 << 4;
    int tid = threadIdx.x, lane = tid & 63, w = tid >> 6;
    int quad = lane >> 4, l15 = lane & 15;
    size_t base = (size_t)b * T_SEQ;

    f16x8 bfr1[4], bfr2[4];
    const f16_t* kr1 = k + (base + sb1 + l15) * HD;
    const f16_t* kr2 = k + (base + sb2 + l15) * HD;
    #pragma unroll
    for (int c = 0; c < 4; ++c) {
        bfr1[c] = *(const f16x8*)(kr1 + c * 32 + quad * 8);
        bfr2[c] = *(const f16x8*)(kr2 + c * 32 + quad * 8);
    }

    float m1 = NEG_INF, l1 = 0.f, m2 = NEG_INF, l2 = 0.f;
    int n1 = 128 - j1;
    int ntot = 129;  // (128-j1) + (128-j2)
    for (int idx = w; idx < ntot; idx += 4) {
        if (idx < n1) cs_step(q, base, (j1 + idx) << 4, sb1, bfr1, m1, l1, quad, l15);
        else          cs_step(q, base, (j2 + idx - n1) << 4, sb2, bfr2, m2, l2, quad, l15);
    }
    if (quad == 0) {
        pm[0][w][l15] = m1; pl[0][w][l15] = l1;
        pm[1][w][l15] = m2; pl[1][w][l15] = l2;
    }
    __syncthreads();
    if (tid < 16) {
        float M = pm[0][0][tid];
        #pragma unroll
        for (int ww = 1; ww < 4; ++ww) M = fmaxf(M, pm[0][ww][tid]);
        float L = 0.f;
        #pragma unroll
        for (int ww = 0; ww < 4; ++ww)
            L += (pl[0][ww][tid] == 0.f) ? 0.f : pl[0][ww][tid] * __expf(pm[0][ww][tid] - M);
        stats[base + sb1 + tid] = make_float2(M, 1.0f / L);
    } else if (tid >= 64 && tid < 80) {
        int c = tid - 64;
        float M = pm[1][0][c];
        #pragma unroll
        for (int ww = 1; ww < 4; ++ww) M = fmaxf(M, pm[1][ww][c]);
        float L = 0.f;
        #pragma unroll
        for (int ww = 0; ww < 4; ++ww)
            L += (pl[1][ww][c] == 0.f) ? 0.f : pl[1][ww][c] * __expf(pm[1][ww][c] - M);
        stats[base + sb2 + c] = make_float2(M, 1.0f / L);
    }
}

// ---------------------------------------------------------------------------
// Kernel 4: output pass, triangle-paired. Block = q-tiles {j, 127-j} (16 rows
// each); 4 waves split the combined 65 s-chunks (32 wide) round-robin, with
// separate partial-O accumulators per tile; LDS float-atomic reduction.
// ---------------------------------------------------------------------------
__device__ __forceinline__ void at_step(
    const f16_t* __restrict__ k, const f16_t* __restrict__ vbat,
    const float2* __restrict__ stats, size_t base, int sb, int trow,
    const f16x8 (&afr)[4], f32x4 (&o)[8], f16_t* myP, int quad, int l15) {
    #pragma unroll
    for (int sub = 0; sub < 2; ++sub) {
        f32x4 s = {};
        const f16_t* krow = k + (base + sb + sub * 16 + l15) * HD;
        #pragma unroll
        for (int c = 0; c < 4; ++c) {
            f16x8 bfr = *(const f16x8*)(krow + c * 32 + quad * 8);
            s = __builtin_amdgcn_mfma_f32_16x16x32_f16(afr[c], bfr, s, 0, 0, 0);
        }
        int scol = sb + sub * 16 + l15;
        float2 st = stats[base + scol];
        #pragma unroll
        for (int r = 0; r < 4; ++r) {
            int t = trow + quad * 4 + r;
            float pv = __expf(s[r] - st.x) * st.y;
            if (scol > t) pv = 0.f;   // causal mask
            myP[(quad * 4 + r) * 40 + sub * 16 + l15] = (f16_t)pv;
        }
    }
    // P: C-layout in LDS -> A-layout fragment (wave-private buffer, no barrier)
    f16x8 pa = *(const f16x8*)&myP[l15 * 40 + quad * 8];
    const f16_t* vb = vbat + sb + quad * 8;
    #pragma unroll
    for (int nf = 0; nf < 8; ++nf) {
        f16x8 bfr = *(const f16x8*)(vb + (size_t)(nf * 16 + l15) * T_SEQ);
        o[nf] = __builtin_amdgcn_mfma_f32_16x16x32_f16(pa, bfr, o[nf], 0, 0, 0);
    }
}

__global__ __launch_bounds__(256) void attn_out(
    const f16_t* __restrict__ q, const f16_t* __restrict__ k,
    const f16_t* __restrict__ vt, const float2* __restrict__ stats,
    float* __restrict__ out) {
    __shared__ f16_t Pl[4][16 * 40];
    __shared__ float obuf[2048];
    int bid = blockIdx.x;
    int b = bid >> 6, p = bid & 63;
    int j1 = p, j2 = 127 - p;
    int trow1 = j1 << 4, trow2 = j2 << 4;
    int tid = threadIdx.x, lane = tid & 63, w = tid >> 6;
    int quad = lane >> 4, l15 = lane & 15;
    size_t base = (size_t)b * T_SEQ;
    int n1 = (j1 + 2) >> 1, n2 = (j2 + 2) >> 1;  // n1+n2 == 65

    f16x8 afr1[4], afr2[4];
    {
        const f16_t* qr1 = q + (base + trow1 + l15) * HD;
        const f16_t* qr2 = q + (base + trow2 + l15) * HD;
        #pragma unroll
        for (int c = 0; c < 4; ++c) {
            afr1[c] = *(const f16x8*)(qr1 + c * 32 + quad * 8);
            afr2[c] = *(const f16x8*)(qr2 + c * 32 + quad * 8);
        }
    }

    f32x4 o1[8] = {}, o2[8] = {};
    f16_t* myP = Pl[w];
    const f16_t* vbat = vt + (size_t)b * HD * T_SEQ;

    int ntot = n1 + n2;
    for (int idx = w; idx < ntot; idx += 4) {
        if (idx < n1) at_step(k, vbat, stats, base, idx << 5, trow1, afr1, o1, myP, quad, l15);
        else          at_step(k, vbat, stats, base, (idx - n1) << 5, trow2, afr2, o2, myP, quad, l15);
    }

    // cross-wave reduction + store, one tile at a time
    #pragma unroll
    for (int ph = 0; ph < 2; ++ph) {
        __syncthreads();
        for (int i = tid; i < 2048; i += 256) obuf[i] = 0.f;
        __syncthreads();
        f32x4* o = ph ? o2 : o1;
        #pragma unroll
        for (int nf = 0; nf < 8; ++nf)
            #pragma unroll
            for (int r = 0; r < 4; ++r)
                atomicAdd(&obuf[(quad * 4 + r) * 128 + nf * 16 + l15], o[nf][r]);
        __syncthreads();
        int trow = ph ? trow2 : trow1;
        for (int i = tid; i < 2048; i += 256)
            out[(base + trow + (i >> 7)) * HD + (i & 127)] = obuf[i];
    }
}

// ---------------------------------------------------------------------------
extern "C" void kernel_launch(void* const* d_in, const int* in_sizes, int n_in,
                              void* d_out, int out_size, void* d_ws, size_t ws_size,
                              hipStream_t stream) {
    const float* X  = (const float*)d_in[0];
    const float* Wk = (const float*)d_in[1];
    const float* bk = (const float*)d_in[2];
    const float* Wq = (const float*)d_in[3];
    const float* bq = (const float*)d_in[4];
    const float* Wv = (const float*)d_in[5];
    const float* bv = (const float*)d_in[6];
    float* out = (float*)d_out;

    char* ws = (char*)d_ws;
    const size_t WT_B    = 384 * 1024 * 2;            // 786432
    const size_t BIAS_B  = 2048;                      // 384*4 padded
    const size_t QKV_B   = (size_t)NBATCH * T_SEQ * HD * 2;  // 4 MiB each
    f16_t* Wt    = (f16_t*)ws;
    float* biasc = (float*)(ws + WT_B);
    f16_t* qb    = (f16_t*)(ws + WT_B + BIAS_B);
    f16_t* kb    = (f16_t*)(ws + WT_B + BIAS_B + QKV_B);
    f16_t* vtb   = (f16_t*)(ws + WT_B + BIAS_B + 2 * QKV_B);
    float2* stats = (float2*)(ws + WT_B + BIAS_B + 3 * QKV_B);

    prep_w<<<dim3(384), dim3(256), 0, stream>>>(Wk, bk, Wq, bq, Wv, bv, Wt, biasc);
    qkv_gemm<<<dim3(384), dim3(256), 0, stream>>>(X, Wt, biasc, qb, kb, vtb);
    col_stats<<<dim3(NBATCH * 64), dim3(256), 0, stream>>>(qb, kb, stats);
    attn_out<<<dim3(NBATCH * 64), dim3(256), 0, stream>>>(qb, kb, vtb, stats, out);
}